// Round 9
// baseline (981.755 us; speedup 1.0000x reference)
//
#include <hip/hip_runtime.h>
#include <math.h>

// Problem constants: B=8, H=W=32 -> L=1024, C=768, nH=12, hd=64, qkv dim 2304.
#define NB 8
#define SL 1024
#define CD 768
#define NHH 12
#define HD 64
#define QKVD 2304

// RESOLVED (R8 probe): d_out is FP32 (reference output dtype; harness reads
// np.float32). Inputs are FP32. R1-R7's only bug was bf16-packing the output.
// R3==R4==R7 bit-identical error proves the tiled pipeline computes the same
// values as the naive one => tiled kernels are correct. This round: tiled
// pipeline + fp32 output stores.

__host__ __device__ __forceinline__ float bf2f(unsigned short u) {
  union { unsigned int i; float f; } v; v.i = ((unsigned int)u) << 16; return v.f;
}
__host__ __device__ __forceinline__ unsigned short f2bf(float f) {
  union { float ff; unsigned int i; } v; v.ff = f;
  unsigned int x = v.i;
  x += 0x7FFFu + ((x >> 16) & 1u);  // RNE
  return (unsigned short)(x >> 16);
}

// C[M,N] = A[M,K] @ B[N,K]^T.  AF32: A is fp32 (else bf16). CF32: C store fp32 (else bf16).
// B always fp32. 64x64 tile, BK=16, 256 threads, 4x4 micro-tile.
template <int AF32, int CF32>
__global__ __launch_bounds__(256) void gemm_abt(
    const void* __restrict__ Av, const float* __restrict__ B,
    void* __restrict__ Cv, int M, int N, int K)
{
  __shared__ float As[16][68];  // [k][m]
  __shared__ float Bs[16][68];  // [k][n]
  const int m0 = blockIdx.y * 64;
  const int n0 = blockIdx.x * 64;
  const int t  = threadIdx.x;
  const int lr = t >> 2;          // 0..63 row within tile
  const int lk = (t & 3) << 2;    // 0,4,8,12 k-offset
  const int tx = t & 15, ty = t >> 4;
  float acc[4][4] = {{0.f, 0.f, 0.f, 0.f}};
  for (int k0 = 0; k0 < K; k0 += 16) {
    const size_t ai = (size_t)(m0 + lr) * K + k0 + lk;
    const size_t bi = (size_t)(n0 + lr) * K + k0 + lk;
    float a0, a1, a2, a3;
    if (AF32) {
      float4 v = *(const float4*)((const float*)Av + ai);
      a0 = v.x; a1 = v.y; a2 = v.z; a3 = v.w;
    } else {
      ushort4 v = *(const ushort4*)((const unsigned short*)Av + ai);
      a0 = bf2f(v.x); a1 = bf2f(v.y); a2 = bf2f(v.z); a3 = bf2f(v.w);
    }
    float4 bv4 = *(const float4*)(B + bi);
    As[lk + 0][lr] = a0;    As[lk + 1][lr] = a1;
    As[lk + 2][lr] = a2;    As[lk + 3][lr] = a3;
    Bs[lk + 0][lr] = bv4.x; Bs[lk + 1][lr] = bv4.y;
    Bs[lk + 2][lr] = bv4.z; Bs[lk + 3][lr] = bv4.w;
    __syncthreads();
#pragma unroll
    for (int k = 0; k < 16; ++k) {
      float4 av = *(const float4*)&As[k][ty << 2];
      float4 bv = *(const float4*)&Bs[k][tx << 2];
      float a_[4] = {av.x, av.y, av.z, av.w};
      float b_[4] = {bv.x, bv.y, bv.z, bv.w};
#pragma unroll
      for (int i = 0; i < 4; ++i)
#pragma unroll
        for (int j = 0; j < 4; ++j) acc[i][j] += a_[i] * b_[j];
    }
    __syncthreads();
  }
#pragma unroll
  for (int i = 0; i < 4; ++i) {
    size_t row = (size_t)(m0 + (ty << 2) + i) * N + n0 + (tx << 2);
    if (CF32) {
      *(float4*)((float*)Cv + row) =
          make_float4(acc[i][0], acc[i][1], acc[i][2], acc[i][3]);
    } else {
      ushort4 o;
      o.x = f2bf(acc[i][0]); o.y = f2bf(acc[i][1]);
      o.z = f2bf(acc[i][2]); o.w = f2bf(acc[i][3]);
      *(ushort4*)((unsigned short*)Cv + row) = o;
    }
  }
}

// RMSNorm (over hd=64) + RoPE in place on q(s=0), k(s=1) planes of bf16 qkv ws.
// One 64-lane wave per (b,l,s,h) vector. Gammas fp32.
__global__ __launch_bounds__(256) void rmsrope_kernel(
    unsigned short* __restrict__ qkv,
    const float* __restrict__ qg, const float* __restrict__ kg)
{
  const int wid  = (int)((blockIdx.x * blockDim.x + threadIdx.x) >> 6);
  const int lane = threadIdx.x & 63;
  const int h = wid % NHH;
  const int s = (wid / NHH) & 1;
  const int l = (wid / (2 * NHH)) % SL;
  const int b = wid / (2 * NHH * SL);
  unsigned short* p = qkv + (((size_t)(b * SL + l) * 3 + s) * NHH + h) * HD + lane;
  float v = bf2f(*p);
  float ss = v * v;
#pragma unroll
  for (int off = 32; off; off >>= 1) ss += __shfl_xor(ss, off);
  float g = s ? kg[lane] : qg[lane];
  v = v * rsqrtf(ss * (1.0f / 64.0f) + 1e-6f) * g;
  float partner = __shfl_xor(v, 32);
  const int j = lane & 31;
  // inv_freq = 10000^(-j/32) = 2^(-log2(10000)*j/32)
  float ang = (float)l * exp2f((float)j * (-13.287712379549449f / 32.0f));
  float sn, cs;
  sincosf(ang, &sn, &cs);
  *p = f2bf((lane < 32) ? (v * cs - partner * sn) : (partner * sn + v * cs));
}

// Flash attention: one block per (q-tile 64, head, batch). qkv bf16 ws; ctx bf16 [B][L][C].
__global__ __launch_bounds__(256) void attn_kernel(
    const unsigned short* __restrict__ qkv, unsigned short* __restrict__ ctx)
{
  __shared__ float Qs[64][68];   // [e][qrow]
  __shared__ float KPs[64][68];  // K phase: [e][krow]; P phase: [qrow][key]  (aliased)
  __shared__ float Vs[64][68];   // [krow][e]
  const int qt = blockIdx.x, h = blockIdx.y, b = blockIdx.z;
  const int t  = threadIdx.x;
  const int lr = t >> 2;          // tile row 0..63
  const int le = (t & 3) << 4;    // e-offset 0,16,32,48
  const int tx = t & 15, ty = t >> 4;
  {
    const unsigned short* qp =
        qkv + (((size_t)(b * SL + qt * 64 + lr) * 3 + 0) * NHH + h) * HD + le;
#pragma unroll
    for (int q = 0; q < 4; ++q) {
      ushort4 u = *(const ushort4*)(qp + (q << 2));
      Qs[le + (q << 2) + 0][lr] = bf2f(u.x);
      Qs[le + (q << 2) + 1][lr] = bf2f(u.y);
      Qs[le + (q << 2) + 2][lr] = bf2f(u.z);
      Qs[le + (q << 2) + 3][lr] = bf2f(u.w);
    }
  }
  float m_i[4], l_i[4], o[4][4];
#pragma unroll
  for (int i = 0; i < 4; ++i) {
    m_i[i] = -INFINITY; l_i[i] = 0.f;
#pragma unroll
    for (int j = 0; j < 4; ++j) o[i][j] = 0.f;
  }
  for (int kt = 0; kt < 16; ++kt) {
    __syncthreads();  // prior iter done reading KPs/Vs; covers Qs stores on kt=0
    {
      const unsigned short* kp =
          qkv + (((size_t)(b * SL + kt * 64 + lr) * 3 + 1) * NHH + h) * HD + le;
      const unsigned short* vp =
          qkv + (((size_t)(b * SL + kt * 64 + lr) * 3 + 2) * NHH + h) * HD + le;
#pragma unroll
      for (int q = 0; q < 4; ++q) {
        ushort4 u = *(const ushort4*)(kp + (q << 2));
        KPs[le + (q << 2) + 0][lr] = bf2f(u.x);
        KPs[le + (q << 2) + 1][lr] = bf2f(u.y);
        KPs[le + (q << 2) + 2][lr] = bf2f(u.z);
        KPs[le + (q << 2) + 3][lr] = bf2f(u.w);
        ushort4 w = *(const ushort4*)(vp + (q << 2));
        *(float4*)&Vs[lr][le + (q << 2)] =
            make_float4(bf2f(w.x), bf2f(w.y), bf2f(w.z), bf2f(w.w));
      }
    }
    __syncthreads();
    float s[4][4] = {{0.f, 0.f, 0.f, 0.f}};
#pragma unroll 16
    for (int e = 0; e < 64; ++e) {
      float4 av = *(const float4*)&Qs[e][ty << 2];
      float4 bv = *(const float4*)&KPs[e][tx << 2];
      float a_[4] = {av.x, av.y, av.z, av.w};
      float b_[4] = {bv.x, bv.y, bv.z, bv.w};
#pragma unroll
      for (int i = 0; i < 4; ++i)
#pragma unroll
        for (int j = 0; j < 4; ++j) s[i][j] += a_[i] * b_[j];
    }
    __syncthreads();  // all threads done reading K before P overwrites KPs
#pragma unroll
    for (int i = 0; i < 4; ++i) {
      float tm = -INFINITY;
#pragma unroll
      for (int j = 0; j < 4; ++j) { s[i][j] *= 0.125f; tm = fmaxf(tm, s[i][j]); }
#pragma unroll
      for (int off = 8; off; off >>= 1) tm = fmaxf(tm, __shfl_xor(tm, off));
      float mn = fmaxf(m_i[i], tm);
      float al = __expf(m_i[i] - mn);
      m_i[i] = mn;
      float p0 = __expf(s[i][0] - mn), p1 = __expf(s[i][1] - mn);
      float p2 = __expf(s[i][2] - mn), p3 = __expf(s[i][3] - mn);
      *(float4*)&KPs[(ty << 2) + i][tx << 2] = make_float4(p0, p1, p2, p3);
      float rs = p0 + p1 + p2 + p3;
#pragma unroll
      for (int off = 8; off; off >>= 1) rs += __shfl_xor(rs, off);
      l_i[i] = l_i[i] * al + rs;
#pragma unroll
      for (int j = 0; j < 4; ++j) o[i][j] *= al;
    }
    __syncthreads();  // P visible to all
#pragma unroll 8
    for (int kk = 0; kk < 64; ++kk) {
      float4 vv = *(const float4*)&Vs[kk][tx << 2];
      float v_[4] = {vv.x, vv.y, vv.z, vv.w};
#pragma unroll
      for (int i = 0; i < 4; ++i) {
        float pv = KPs[(ty << 2) + i][kk];
#pragma unroll
        for (int j = 0; j < 4; ++j) o[i][j] += pv * v_[j];
      }
    }
  }
#pragma unroll
  for (int i = 0; i < 4; ++i) {
    float inv = 1.f / l_i[i];
    size_t row = (size_t)(b * SL + qt * 64 + (ty << 2) + i) * CD + h * HD + (tx << 2);
    ushort4 ob;
    ob.x = f2bf(o[i][0] * inv); ob.y = f2bf(o[i][1] * inv);
    ob.z = f2bf(o[i][2] * inv); ob.w = f2bf(o[i][3] * inv);
    *(ushort4*)(ctx + row) = ob;
  }
}

extern "C" void kernel_launch(void* const* d_in, const int* in_sizes, int n_in,
                              void* d_out, int out_size, void* d_ws, size_t ws_size,
                              hipStream_t stream) {
  const void*  x     = d_in[0];                 // (8,32,32,768) fp32
  const float* w_qkv = (const float*)d_in[1];   // (2304,768) fp32
  const float* qg    = (const float*)d_in[2];   // (64,) fp32
  const float* kg    = (const float*)d_in[3];   // (64,) fp32
  const float* w_out = (const float*)d_in[4];   // (768,768) fp32
  // d_out: fp32 (reference output dtype) — confirmed by R8 probe.

  // ws: qkv bf16 [8192][2304] = 37.75MB | ctx bf16 [8192][768] = 12.6MB
  unsigned short* qkv = (unsigned short*)d_ws;
  unsigned short* ctx = qkv + (size_t)NB * SL * QKVD;

  const int M = NB * SL;  // 8192
  dim3 blk(256);
  // 1) qkv = x @ w_qkv^T  (fp32 A, bf16 out)
  gemm_abt<1, 0><<<dim3(QKVD / 64, M / 64), blk, 0, stream>>>(
      x, w_qkv, qkv, M, QKVD, CD);
  // 2) rmsnorm + rope on q,k in place
  rmsrope_kernel<<<dim3(NB * SL * 2 * NHH / 4), blk, 0, stream>>>(qkv, qg, kg);
  // 3) attention -> ctx (bf16)
  attn_kernel<<<dim3(SL / 64, NHH, NB), blk, 0, stream>>>(qkv, ctx);
  // 4) out = ctx @ w_out^T  (bf16 A, fp32 out)
  gemm_abt<0, 1><<<dim3(CD / 64, M / 64), blk, 0, stream>>>(
      ctx, w_out, d_out, M, CD, CD);
}

// Round 10
// 342.096 us; speedup vs baseline: 2.8698x; 2.8698x over previous
//
#include <hip/hip_runtime.h>
#include <math.h>

// Problem: B=8, L=1024, C=768, nH=12, hd=64, qkv dim 2304. fp32 in, fp32 out.
#define NB 8
#define SL 1024
#define CD 768
#define NHH 12
#define HD 64
#define QKVD 2304

typedef __attribute__((ext_vector_type(8))) __bf16 bf16x8;
typedef __attribute__((ext_vector_type(8))) unsigned short u16x8;
typedef __attribute__((ext_vector_type(4))) float f32x4;
#define MFMA16(a, b, c) __builtin_amdgcn_mfma_f32_16x16x32_bf16(a, b, c, 0, 0, 0)

__host__ __device__ __forceinline__ float bf2f(unsigned short u) {
  union { unsigned int i; float f; } v; v.i = ((unsigned int)u) << 16; return v.f;
}
__host__ __device__ __forceinline__ unsigned short f2bf(float f) {
  union { float ff; unsigned int i; } v; v.ff = f;
  unsigned int x = v.i;
  x += 0x7FFFu + ((x >> 16) & 1u);  // RNE
  return (unsigned short)(x >> 16);
}

// fp32 -> bf16 bulk convert (memory-bound).
__global__ __launch_bounds__(256) void conv_kernel(
    const float4* __restrict__ in, ushort4* __restrict__ out, int n4)
{
  int i = blockIdx.x * 256 + threadIdx.x;
  if (i < n4) {
    float4 v = in[i];
    ushort4 o;
    o.x = f2bf(v.x); o.y = f2bf(v.y); o.z = f2bf(v.z); o.w = f2bf(v.w);
    out[i] = o;
  }
}

// C[M,N] = A[M,K] @ B[N,K]^T, A,B bf16. CF32: store fp32 else bf16.
// 128x128 tile, BK=32, 256 threads = 4 waves in 2x2 grid, each wave 64x64
// via 4x4 grid of 16x16x32 MFMA.
template <int CF32>
__global__ __launch_bounds__(256) void gemm_mfma(
    const unsigned short* __restrict__ A, const unsigned short* __restrict__ B,
    void* __restrict__ Cv, int M, int N, int K)
{
  __shared__ unsigned short As[128][40];  // +8 pad; row = 80B = 5*16B (aligned)
  __shared__ unsigned short Bs[128][40];
  const int m0 = blockIdx.y * 128, n0 = blockIdx.x * 128;
  const int t = threadIdx.x;
  const int wave = t >> 6, lane = t & 63;
  const int wm = (wave >> 1) * 64, wn = (wave & 1) * 64;
  const int lm = lane & 15, quad = lane >> 4;
  const int sr = t >> 2, sq = (t & 3) * 8;  // staging: row, k-offset
  f32x4 acc[4][4];
#pragma unroll
  for (int i = 0; i < 4; ++i)
#pragma unroll
    for (int j = 0; j < 4; ++j)
#pragma unroll
      for (int r = 0; r < 4; ++r) acc[i][j][r] = 0.f;

  for (int k0 = 0; k0 < K; k0 += 32) {
    u16x8 a0 = *(const u16x8*)(A + (size_t)(m0 + sr) * K + k0 + sq);
    u16x8 a1 = *(const u16x8*)(A + (size_t)(m0 + sr + 64) * K + k0 + sq);
    u16x8 b0 = *(const u16x8*)(B + (size_t)(n0 + sr) * K + k0 + sq);
    u16x8 b1 = *(const u16x8*)(B + (size_t)(n0 + sr + 64) * K + k0 + sq);
    *(u16x8*)&As[sr][sq] = a0;
    *(u16x8*)&As[sr + 64][sq] = a1;
    *(u16x8*)&Bs[sr][sq] = b0;
    *(u16x8*)&Bs[sr + 64][sq] = b1;
    __syncthreads();
    bf16x8 af[4], bfr[4];
#pragma unroll
    for (int i = 0; i < 4; ++i)
      af[i] = *(const bf16x8*)&As[wm + i * 16 + lm][quad * 8];
#pragma unroll
    for (int j = 0; j < 4; ++j)
      bfr[j] = *(const bf16x8*)&Bs[wn + j * 16 + lm][quad * 8];
#pragma unroll
    for (int i = 0; i < 4; ++i)
#pragma unroll
      for (int j = 0; j < 4; ++j)
        acc[i][j] = MFMA16(af[i], bfr[j], acc[i][j]);
    __syncthreads();
  }
#pragma unroll
  for (int i = 0; i < 4; ++i) {
    const int row = m0 + wm + i * 16 + quad * 4;
#pragma unroll
    for (int r = 0; r < 4; ++r) {
      const size_t base = (size_t)(row + r) * N + n0 + wn + lm;
#pragma unroll
      for (int j = 0; j < 4; ++j) {
        if (CF32) ((float*)Cv)[base + j * 16] = acc[i][j][r];
        else ((unsigned short*)Cv)[base + j * 16] = f2bf(acc[i][j][r]);
      }
    }
  }
}

// RMSNorm(hd=64) + RoPE in place on q(s=0), k(s=1) planes of bf16 qkv ws.
// One 64-lane wave per (b,l,s,h) vector. Gammas fp32.
__global__ __launch_bounds__(256) void rmsrope_kernel(
    unsigned short* __restrict__ qkv,
    const float* __restrict__ qg, const float* __restrict__ kg)
{
  const int wid  = (int)((blockIdx.x * blockDim.x + threadIdx.x) >> 6);
  const int lane = threadIdx.x & 63;
  const int h = wid % NHH;
  const int s = (wid / NHH) & 1;
  const int l = (wid / (2 * NHH)) % SL;
  const int b = wid / (2 * NHH * SL);
  unsigned short* p = qkv + (((size_t)(b * SL + l) * 3 + s) * NHH + h) * HD + lane;
  float v = bf2f(*p);
  float ss = v * v;
#pragma unroll
  for (int off = 32; off; off >>= 1) ss += __shfl_xor(ss, off);
  float g = s ? kg[lane] : qg[lane];
  v = v * rsqrtf(ss * (1.0f / 64.0f) + 1e-6f) * g;
  float partner = __shfl_xor(v, 32);
  const int j = lane & 31;
  float ang = (float)l * exp2f((float)j * (-13.287712379549449f / 32.0f));
  float sn, cs;
  sincosf(ang, &sn, &cs);
  *p = f2bf((lane < 32) ? (v * cs - partner * sn) : (partner * sn + v * cs));
}

// MFMA flash attention. Block = (qtile 64, head, batch), 256 thr = 4 waves.
// Wave w owns q-rows [w*16, w*16+16) x all 64 keys/dims.
// Q,K fragments load DIRECTLY from global (d-contiguous rows = fragment layout).
// V transposed into LDS; P round-trips LDS (C/D -> A-operand layout).
__global__ __launch_bounds__(256) void attn_mfma(
    const unsigned short* __restrict__ qkv, unsigned short* __restrict__ ctx)
{
  __shared__ unsigned short Vt[64][72];  // [d][key], row 144B = 9*16B
  __shared__ unsigned short Ps[64][72];  // [qrow][key]
  const int qt = blockIdx.x, h = blockIdx.y, b = blockIdx.z;
  const int t = threadIdx.x, wave = t >> 6, lane = t & 63;
  const int lm = lane & 15, quad = lane >> 4;
  const int wq = wave * 16;
  const int vkey = t & 63, vds = (t >> 6) * 16;  // V staging assignment

  bf16x8 qf[2];
  {
    const unsigned short* qp =
        qkv + (((size_t)(b * SL + qt * 64 + wq + lm) * 3 + 0) * NHH + h) * HD;
    qf[0] = *(const bf16x8*)(qp + quad * 8);
    qf[1] = *(const bf16x8*)(qp + 32 + quad * 8);
  }
  f32x4 o[4];
  float m_i[4], l_i[4];
#pragma unroll
  for (int j = 0; j < 4; ++j) {
    m_i[j] = -INFINITY; l_i[j] = 0.f;
#pragma unroll
    for (int r = 0; r < 4; ++r) o[j][r] = 0.f;
  }

  for (int kt = 0; kt < 16; ++kt) {
    // stage V transposed: thread t loads V[key=vkey][vds..vds+16), writes Vt[d][key]
    {
      const unsigned short* vp =
          qkv + (((size_t)(b * SL + kt * 64 + vkey) * 3 + 2) * NHH + h) * HD + vds;
      u16x8 v0 = *(const u16x8*)(vp);
      u16x8 v1 = *(const u16x8*)(vp + 8);
#pragma unroll
      for (int e = 0; e < 8; ++e) {
        Vt[vds + e][vkey] = v0[e];
        Vt[vds + 8 + e][vkey] = v1[e];
      }
    }
    // S = Q K^T (K fragments direct from global)
    f32x4 s[4];
#pragma unroll
    for (int j = 0; j < 4; ++j) {
#pragma unroll
      for (int r = 0; r < 4; ++r) s[j][r] = 0.f;
      const unsigned short* kp =
          qkv + (((size_t)(b * SL + kt * 64 + j * 16 + lm) * 3 + 1) * NHH + h) * HD;
      bf16x8 k0f = *(const bf16x8*)(kp + quad * 8);
      bf16x8 k1f = *(const bf16x8*)(kp + 32 + quad * 8);
      s[j] = MFMA16(qf[0], k0f, s[j]);
      s[j] = MFMA16(qf[1], k1f, s[j]);
    }
    // online softmax per row r (rows quad*4+r, replicated across quad's 16 lanes)
#pragma unroll
    for (int r = 0; r < 4; ++r) {
      float tm = -INFINITY;
#pragma unroll
      for (int j = 0; j < 4; ++j) { s[j][r] *= 0.125f; tm = fmaxf(tm, s[j][r]); }
#pragma unroll
      for (int off = 8; off; off >>= 1) tm = fmaxf(tm, __shfl_xor(tm, off));
      float mn = fmaxf(m_i[r], tm);
      float al = __expf(m_i[r] - mn);
      m_i[r] = mn;
      float rs = 0.f;
#pragma unroll
      for (int j = 0; j < 4; ++j) {
        float p = __expf(s[j][r] - mn);
        rs += p;
        Ps[wq + quad * 4 + r][j * 16 + lm] = f2bf(p);
      }
#pragma unroll
      for (int off = 8; off; off >>= 1) rs += __shfl_xor(rs, off);
      l_i[r] = l_i[r] * al + rs;
#pragma unroll
      for (int j = 0; j < 4; ++j) o[j][r] *= al;
    }
    __syncthreads();  // Vt + Ps visible
    // O += P V
    bf16x8 pf0 = *(const bf16x8*)&Ps[wq + lm][quad * 8];
    bf16x8 pf1 = *(const bf16x8*)&Ps[wq + lm][32 + quad * 8];
#pragma unroll
    for (int j = 0; j < 4; ++j) {
      bf16x8 v0f = *(const bf16x8*)&Vt[j * 16 + lm][quad * 8];
      bf16x8 v1f = *(const bf16x8*)&Vt[j * 16 + lm][32 + quad * 8];
      o[j] = MFMA16(pf0, v0f, o[j]);
      o[j] = MFMA16(pf1, v1f, o[j]);
    }
    __syncthreads();  // PV reads done before next iter overwrites Vt/Ps
  }
#pragma unroll
  for (int r = 0; r < 4; ++r) {
    const float inv = 1.f / l_i[r];
    const size_t row = (size_t)(b * SL + qt * 64 + wq + quad * 4 + r) * CD + h * HD + lm;
#pragma unroll
    for (int j = 0; j < 4; ++j) ctx[row + j * 16] = f2bf(o[j][r] * inv);
  }
}

extern "C" void kernel_launch(void* const* d_in, const int* in_sizes, int n_in,
                              void* d_out, int out_size, void* d_ws, size_t ws_size,
                              hipStream_t stream) {
  const float* x     = (const float*)d_in[0];  // (8,32,32,768) fp32
  const float* w_qkv = (const float*)d_in[1];  // (2304,768) fp32
  const float* qg    = (const float*)d_in[2];  // (64,) fp32
  const float* kg    = (const float*)d_in[3];  // (64,) fp32
  const float* w_out = (const float*)d_in[4];  // (768,768) fp32
  // d_out: fp32 (confirmed R8/R9).

  // ws: xb[8192*768] | wqb[2304*768] | wob[768*768] | qkv[8192*2304] | ctx[8192*768]  (bf16)
  unsigned short* xb  = (unsigned short*)d_ws;
  unsigned short* wqb = xb + (size_t)NB * SL * CD;
  unsigned short* wob = wqb + (size_t)QKVD * CD;
  unsigned short* qkv = wob + (size_t)CD * CD;
  unsigned short* ctx = qkv + (size_t)NB * SL * QKVD;

  const int M = NB * SL;  // 8192
  dim3 blk(256);
  // 0) fp32 -> bf16 converts
  conv_kernel<<<dim3(M * CD / 4 / 256), blk, 0, stream>>>(
      (const float4*)x, (ushort4*)xb, M * CD / 4);
  conv_kernel<<<dim3(QKVD * CD / 4 / 256), blk, 0, stream>>>(
      (const float4*)w_qkv, (ushort4*)wqb, QKVD * CD / 4);
  conv_kernel<<<dim3(CD * CD / 4 / 256), blk, 0, stream>>>(
      (const float4*)w_out, (ushort4*)wob, CD * CD / 4);
  // 1) qkv = x @ w_qkv^T  (bf16 out)
  gemm_mfma<0><<<dim3(QKVD / 128, M / 128), blk, 0, stream>>>(
      xb, wqb, qkv, M, QKVD, CD);
  // 2) rmsnorm + rope on q,k in place
  rmsrope_kernel<<<dim3(NB * SL * 2 * NHH / 4), blk, 0, stream>>>(qkv, qg, kg);
  // 3) attention -> ctx (bf16)
  attn_mfma<<<dim3(SL / 64, NHH, NB), blk, 0, stream>>>(qkv, ctx);
  // 4) out = ctx @ w_out^T  (fp32 out)
  gemm_mfma<1><<<dim3(CD / 128, M / 128), blk, 0, stream>>>(
      ctx, wob, d_out, M, CD, CD);
}